// Round 10
// baseline (614.993 us; speedup 1.0000x reference)
//
#include <hip/hip_runtime.h>
#include <hip/hip_bf16.h>

// ---------------------------------------------------------------------------
// Types / helpers
// ---------------------------------------------------------------------------
typedef __bf16 bf16x8 __attribute__((ext_vector_type(8)));
typedef float f32x4 __attribute__((ext_vector_type(4)));
typedef unsigned short u16x4 __attribute__((ext_vector_type(4)));

// fp32 -> bf16 bits, round-to-nearest-even (inputs are finite; no NaN path)
__device__ __forceinline__ unsigned short f2bs(float f) {
    unsigned u = __builtin_bit_cast(unsigned, f);
    u = (u + 0x7fffu + ((u >> 16) & 1u)) >> 16;
    return (unsigned short)u;
}
__device__ __forceinline__ float bs2f(unsigned short s) {
    unsigned u = ((unsigned)s) << 16;
    return __builtin_bit_cast(float, u);
}

#define GLDS16(gp, lp)                                                        \
    __builtin_amdgcn_global_load_lds(                                         \
        (const __attribute__((address_space(1))) void*)(gp),                  \
        (__attribute__((address_space(3))) void*)(lp), 16, 0, 0)

// R18 feats config kept (TCHUNK=16 + unroll-4: ~10us, banked).
#define TCHUNK 16

// Kernel 1a: per-chunk sums + write the h-half of X in bf16. Vectorized x4.
__global__ __launch_bounds__(192) void feats_partial(
    const float* __restrict__ h, float* __restrict__ partial,
    unsigned short* __restrict__ X, int B, int T, int D, int nC) {
    const int d4 = threadIdx.x * 4;       // 0..764
    const int b = blockIdx.x, c = blockIdx.y;
    const int t0 = c * TCHUNK;
    const int t1 = min(t0 + TCHUNK, T);
    const float* hp = h + ((long)b * T + t0) * D + d4;
    unsigned short* xp = X + ((long)b * T + t0) * (2 * D) + D + d4;
    f32x4 s = {0.f, 0.f, 0.f, 0.f};
    #pragma unroll 4
    for (int t = t0; t < t1; ++t) {
        f32x4 v = *(const f32x4*)hp;
        u16x4 o;
        #pragma unroll
        for (int i = 0; i < 4; ++i) o[i] = f2bs(v[i]);
        *(u16x4*)xp = o;
        s += v;
        hp += D;
        xp += 2 * D;
    }
    *(f32x4*)(partial + ((long)b * nC + c) * D + d4) = s;
}

// Kernel 1b: write the prefix-mean half. Vectorized x4.
// R14 fix kept: running sum reads h (fp32, distinct restrict pointer).
__global__ __launch_bounds__(192) void feats_write(
    const float* __restrict__ h, const float* __restrict__ partial,
    unsigned short* __restrict__ X, int B, int T, int D, int nC) {
    const int d4 = threadIdx.x * 4;
    const int b = blockIdx.x, c = blockIdx.y;
    const int t0 = c * TCHUNK;
    const int t1 = min(t0 + TCHUNK, T);
    f32x4 sum = {0.f, 0.f, 0.f, 0.f};
    #pragma unroll 4
    for (int cc = 0; cc < c; ++cc)
        sum += *(const f32x4*)(partial + ((long)b * nC + cc) * D + d4);
    const float* hp = h + ((long)b * T + t0) * D + d4;
    unsigned short* xp = X + ((long)b * T + t0) * (2 * D) + d4;
    #pragma unroll 4
    for (int t = t0; t < t1; ++t) {
        const float inv = (t == 0) ? 0.f : 1.0f / (float)t;
        u16x4 o;
        #pragma unroll
        for (int i = 0; i < 4; ++i) o[i] = f2bs(sum[i] * inv);
        *(u16x4*)xp = o;
        f32x4 v = *(const f32x4*)hp;
        sum += v;
        hp += D;
        xp += 2 * D;
    }
}

// ---------------------------------------------------------------------------
// Kernel 2: transpose + cast. W: [K][N] fp32 -> WT: [N][K] bf16 bits.
// ---------------------------------------------------------------------------
__global__ __launch_bounds__(256) void transpose_cast(
    const float* __restrict__ W, unsigned short* __restrict__ WT,
    int K, int N) {
    __shared__ float tile[32][33];
    const int n0 = blockIdx.x * 32, k0 = blockIdx.y * 32;
    const int tx = threadIdx.x, ty = threadIdx.y;
    #pragma unroll
    for (int i = ty; i < 32; i += 8)
        tile[i][tx] = W[(long)(k0 + i) * N + n0 + tx];
    __syncthreads();
    #pragma unroll
    for (int i = ty; i < 32; i += 8)
        WT[(long)(n0 + i) * K + k0 + tx] = f2bs(tile[tx][i]);
}

__global__ __launch_bounds__(256) void init_out(
    float* __restrict__ out, const float* __restrict__ b3, int M) {
    int m = blockIdx.x * 256 + threadIdx.x;
    if (m < M) out[m] = b3[0];
}

// ---------------------------------------------------------------------------
// Kernel 3: GEMM  C[M,N] = relu(A[M,K] * BT[N,K]^T + bias)
//
// R19: 128x128 tile / 256 threads / 2 BLOCKS PER CU.
// MECHANISM (new, not a schedule mutation): R17 per-K-tile wall 5325cy vs
// 2484cy MFMA-pipe demand; gap = barrier sync + cold post-barrier ds_read
// chains + gate waits, NAKED because 128KiB LDS pins 1 block/CU -> all 8
// waves stall together. 64KiB LDS + 64-acc tile -> 2 INDEPENDENT blocks/CU
// (same 8 waves/CU, two desynced barrier domains; m114 overlap).
// Skeleton carried over VERBATIM from R13/R17: staging units still 2
// loads/thread (512 chunks/256 thr) -> vmcnt(6)/vmcnt(0) gate arithmetic,
// 3 barriers/K-tile, stage placement, double-XOR swizzle both-sides,
// prologue order, 16x16 frag formulas. Only geometry constants halved:
// 4 waves 2Mx2N, 64x64/wave, acc[4][4] f32x4 = 64 regs, A-frags 4, B-frags
// 4, per plane: {RD_B x4, 2x(RD_A x2 + 8 MFMA)}.
// PRE-COMMIT: if GEMM1 >= 210us, inter-block desync doesn't pay -> the
// structure is intra-dependency-bound; accept or stop.
// LEDGER (do not retry): R12 2-bar merge -7%; R14 frag-major LDS -23%
// (bank-conflict counter benign); R15 split-gate -7%; R16 feats instr-vec
// null. No min-waves bounds (R4); acc budget respected (R8).
// C/D: col=lane&15, row=(lane>>4)*4+reg (m89/m91).
// ---------------------------------------------------------------------------

#define RD_A(dst, c, g, ks)                                                   \
    _Pragma("unroll")                                                         \
    for (int fr_ = 0; fr_ < 2; ++fr_)                                         \
        dst[fr_] = *(const bf16x8*)(&lds[(c)][0][(ks)][0] +                   \
                                    baseA16[(g) * 2 + fr_]);

#define RD_B(dst, c, ks)                                                      \
    _Pragma("unroll")                                                         \
    for (int fc_ = 0; fc_ < 4; ++fc_)                                         \
        dst[fc_] = *(const bf16x8*)(&lds[(c)][1][(ks)][0] + baseB16[fc_]);

#define MM16(g, AF, BF)                                                       \
    __builtin_amdgcn_s_setprio(1);                                            \
    _Pragma("unroll")                                                         \
    for (int fr_ = 0; fr_ < 2; ++fr_)                                         \
        _Pragma("unroll")                                                     \
        for (int fc_ = 0; fc_ < 4; ++fc_)                                     \
            acc[(g) * 2 + fr_][fc_] = __builtin_amdgcn_mfma_f32_16x16x32_bf16(\
                AF[fr_], BF[fc_], acc[(g) * 2 + fr_][fc_], 0, 0, 0);          \
    __builtin_amdgcn_s_setprio(0);

#define BAR()                                                                 \
    __builtin_amdgcn_sched_barrier(0);                                        \
    __builtin_amdgcn_s_barrier();                                             \
    __builtin_amdgcn_sched_barrier(0);

#define GROUP(c, o, t)                                                        \
  {                                                                           \
    /* stretch 1: stage next A-Kh1, gate on tile t, sync (R13-exact) */       \
    if ((t) + 1 < NT) stageA(o, 1, (t) + 1);                                  \
    if ((t) == NT - 1)                                                        \
        asm volatile("s_waitcnt vmcnt(0)" ::: "memory");                      \
    else                                                                      \
        asm volatile("s_waitcnt vmcnt(6)" ::: "memory");                      \
    BAR();                                                                    \
    /* stretch 2: plane 0; B read once, 2 A-groups */                         \
    {                                                                         \
        bf16x8 bfr[4];                                                        \
        RD_B(bfr, c, 0);                                                      \
        {                                                                     \
            bf16x8 af[2];                                                     \
            RD_A(af, c, 0, 0);                                                \
            MM16(0, af, bfr);                                                 \
        }                                                                     \
        if ((t) + 1 < NT) stageB(o, 1, (t) + 1);                              \
        {                                                                     \
            bf16x8 af[2];                                                     \
            RD_A(af, c, 1, 0);                                                \
            MM16(1, af, bfr);                                                 \
        }                                                                     \
    }                                                                         \
    BAR();                                                                    \
    /* stretch 3: plane 1; stage Kh0(t+2) into freed planes */                \
    {                                                                         \
        bf16x8 bfr[4];                                                        \
        if ((t) + 2 < NT) stageA(c, 0, (t) + 2);                              \
        RD_B(bfr, c, 1);                                                      \
        {                                                                     \
            bf16x8 af[2];                                                     \
            RD_A(af, c, 0, 1);                                                \
            MM16(0, af, bfr);                                                 \
        }                                                                     \
        if ((t) + 2 < NT) stageB(c, 0, (t) + 2);                              \
        {                                                                     \
            bf16x8 af[2];                                                     \
            RD_A(af, c, 1, 1);                                                \
            MM16(1, af, bfr);                                                 \
        }                                                                     \
    }                                                                         \
    BAR();                                                                    \
  }

template <bool FUSE>
__global__ __launch_bounds__(256) void gemm_bt_bias_relu(
    const unsigned short* __restrict__ A,   // [M,K] bf16 bits
    const unsigned short* __restrict__ BT,  // [N,K] bf16 bits
    const float* __restrict__ bias,         // [N]
    unsigned short* __restrict__ C,         // [M,N] bf16 bits (unused if FUSE)
    const float* __restrict__ W3,           // [N] head weights (FUSE only)
    float* __restrict__ outp,               // [M] (FUSE only)
    int M, int N, int K) {
    // [dbuf][A=0/B=1][plane][128 rows x 32 elems] : 64 KiB -> 2 blocks/CU
    __shared__ __align__(16) unsigned short lds[2][2][2][4096];

    const int tid = threadIdx.x;
    const int lane = tid & 63;
    const int wave = tid >> 6;
    const int wm = wave >> 1;   // 0..1 -> rows wm*64..+63
    const int wn = wave & 1;    // 0..1 -> cols wn*64..+63
    const int l15 = lane & 15;
    const int q4 = lane >> 4;   // 0..3

    // ---- m204 bijective XCD chunking over a row-supertile order ----
    const int nRow = M >> 7;            // 254
    const int nCol = N >> 7;            // 16 (GEMM1) / 8 (GEMM2)
    const int nwg = nRow * nCol;
    const int q = nwg >> 3, r = nwg & 7;
    const int x = blockIdx.x & 7;
    const int sidx = blockIdx.x >> 3;
    const int L = (x < r ? x * (q + 1) : r * (q + 1) + (x - r) * q) + sidx;
    const int perSup = 8 * nCol;
    const int nFull = nRow >> 3;        // 31
    const int fullL = nFull * perSup;
    int row_blk, col_blk;
    if (L < fullL) {
        const int sup = L / perSup;
        const int w = L - sup * perSup;
        row_blk = sup * 8 + (w & 7);
        col_blk = w >> 3;
    } else {
        const int rem = L - fullL;
        const int rt = nRow - nFull * 8;  // 6
        row_blk = nFull * 8 + rem % rt;
        col_blk = rem / rt;
    }
    const long row0 = (long)row_blk * 128;
    const long col0 = (long)col_blk * 128;

    // ---- staging source (pre-swizzled global col, rule 21) ----
    // thread covers 16B chunk: row = tid>>2 (+64 for 2nd load), slot=tid&3.
    // global chunk = slot ^ swz(row), swz(r) = ((r>>1)&3) ^ ((r>>3)&3);
    // +64-row offset leaves swz bits (1,2,3,4) unchanged.
    const int sg = ((tid & 3) ^ ((tid >> 3) & 3) ^ ((tid >> 5) & 3)) * 8;
    const unsigned short* Ab = A + (row0 + (tid >> 2)) * K + sg;
    const unsigned short* Bb = BT + (col0 + (tid >> 2)) * K + sg;

    auto stageA = [&](int c, int kh, int kt) {
        GLDS16(Ab + (long)kt * 64 + kh * 32, &lds[c][0][kh][tid * 8]);
        GLDS16(Ab + (long)64 * K + (long)kt * 64 + kh * 32,
               &lds[c][0][kh][(256 + tid) * 8]);
    };
    auto stageB = [&](int c, int kh, int kt) {
        GLDS16(Bb + (long)kt * 64 + kh * 32, &lds[c][1][kh][tid * 8]);
        GLDS16(Bb + (long)64 * K + (long)kt * 64 + kh * 32,
               &lds[c][1][kh][(256 + tid) * 8]);
    };

    // ---- per-lane LDS read offsets for 16x16 frags ----
    // frag (i, ks): row = wm*64 + i*16 + l15, k = ks*32 + q4*8 + j
    // plane = ks, chunk = q4, slot = chunk ^ ((row>>1)&3) ^ ((row>>3)&3)
    int baseA16[4], baseB16[4];
    #pragma unroll
    for (int i = 0; i < 4; ++i) {
        int ra = wm * 64 + i * 16 + l15;
        baseA16[i] = ra * 32 + ((q4 ^ ((ra >> 1) & 3) ^ ((ra >> 3) & 3)) * 8);
    }
    #pragma unroll
    for (int fc = 0; fc < 4; ++fc) {
        int rb = wn * 64 + fc * 16 + l15;
        baseB16[fc] = rb * 32 + ((q4 ^ ((rb >> 1) & 3) ^ ((rb >> 3) & 3)) * 8);
    }

    f32x4 acc[4][4];
    #pragma unroll
    for (int i = 0; i < 4; ++i)
        #pragma unroll
        for (int j = 0; j < 4; ++j)
            acc[i][j] = (f32x4)(0.f);

    const int NT = K >> 6;  // K-tiles of 64 (24 / 32 here; even)

    // ---- prologue: tile0 (4 units) + tile1 Kh0 (2 units), 12 loads ----
    stageA(0, 0, 0); stageB(0, 0, 0);
    stageA(0, 1, 0); stageB(0, 1, 0);
    stageA(1, 0, 1); stageB(1, 0, 1);

    for (int t = 0; t < NT; t += 2) {
        GROUP(0, 1, t);
        GROUP(1, 0, t + 1);
    }

    // Epilogue. 16x16 C/D: col=lane&15, row=(lane>>4)*4+reg (m89/m91)
    if (!FUSE) {
        float bv[4];
        #pragma unroll
        for (int fc = 0; fc < 4; ++fc)
            bv[fc] = bias[col0 + wn * 64 + fc * 16 + l15];
        #pragma unroll
        for (int fr = 0; fr < 4; ++fr) {
            #pragma unroll
            for (int reg = 0; reg < 4; ++reg) {
                const long row = row0 + wm * 64 + fr * 16 + q4 * 4 + reg;
                #pragma unroll
                for (int fc = 0; fc < 4; ++fc) {
                    const long col = col0 + wn * 64 + fc * 16 + l15;
                    float v = fmaxf(acc[fr][fc][reg] + bv[fc], 0.f);
                    C[row * N + col] = f2bs(v);
                }
            }
        }
    } else {
        float w3v[4], bv[4];
        #pragma unroll
        for (int fc = 0; fc < 4; ++fc) {
            const long col = col0 + wn * 64 + fc * 16 + l15;
            w3v[fc] = W3[col];
            bv[fc] = bias[col];
        }
        #pragma unroll
        for (int fr = 0; fr < 4; ++fr) {
            #pragma unroll
            for (int reg = 0; reg < 4; ++reg) {
                float s = 0.f;
                #pragma unroll
                for (int fc = 0; fc < 4; ++fc)
                    s += fmaxf(acc[fr][fc][reg] + bv[fc], 0.f) * w3v[fc];
                s += __shfl_xor(s, 1, 64);
                s += __shfl_xor(s, 2, 64);
                s += __shfl_xor(s, 4, 64);
                s += __shfl_xor(s, 8, 64);
                if (l15 == 0) {
                    const long row = row0 + wm * 64 + fr * 16 + q4 * 4 + reg;
                    atomicAdd(&outp[row], s);
                }
            }
        }
    }
}

// ---------------------------------------------------------------------------
// Launch
// ---------------------------------------------------------------------------
extern "C" void kernel_launch(void* const* d_in, const int* in_sizes, int n_in,
                              void* d_out, int out_size, void* d_ws,
                              size_t ws_size, hipStream_t stream) {
    const float* h  = (const float*)d_in[0];
    const float* W1 = (const float*)d_in[1];
    const float* b1 = (const float*)d_in[2];
    const float* W2 = (const float*)d_in[3];
    const float* b2 = (const float*)d_in[4];
    const float* W3 = (const float*)d_in[5];
    const float* b3 = (const float*)d_in[6];
    float* out = (float*)d_out;

    const int B = 128, T = 254, D = 768, H = 1024;
    const int M = B * T;        // 32512 = 254 * 128
    const int K1 = 2 * D;       // 1536
    const int N1 = 2 * H;       // 2048
    const int K2 = N1;          // 2048
    const int N2 = H;           // 1024
    const int nC = (T + TCHUNK - 1) / TCHUNK;  // 16

    char* ws = (char*)d_ws;
    size_t off = 0;
    auto alloc = [&](size_t bytes) {
        char* p = ws + off;
        off += (bytes + 255) & ~(size_t)255;
        return p;
    };
    unsigned short* X   = (unsigned short*)alloc((size_t)M * K1 * 2);  // 99.9 MB
    unsigned short* H1  = (unsigned short*)alloc((size_t)M * N1 * 2);  // 133.2 MB
    unsigned short* W1T = (unsigned short*)alloc((size_t)N1 * K1 * 2); // 6.3 MB
    unsigned short* W2T = (unsigned short*)alloc((size_t)N2 * K2 * 2); // 4.2 MB
    float* partial      = (float*)alloc((size_t)B * nC * D * 4);       // 6.3 MB

    dim3 tb(32, 8);
    transpose_cast<<<dim3(N1 / 32, K1 / 32), tb, 0, stream>>>(W1, W1T, K1, N1);
    transpose_cast<<<dim3(N2 / 32, K2 / 32), tb, 0, stream>>>(W2, W2T, K2, N2);

    feats_partial<<<dim3(B, nC), 192, 0, stream>>>(h, partial, X, B, T, D, nC);
    feats_write<<<dim3(B, nC), 192, 0, stream>>>(h, partial, X, B, T, D, nC);

    init_out<<<dim3((M + 255) / 256), 256, 0, stream>>>(out, b3, M);

    // 128x128 tiles, 256 threads, 2 blocks/CU, R13 skeleton + 16x16 core
    gemm_bt_bias_relu<false><<<dim3((M / 128) * (N1 / 128)), 256, 0, stream>>>(
        X, W1T, b1, H1, nullptr, nullptr, M, N1, K1);
    gemm_bt_bias_relu<true><<<dim3((M / 128) * (N2 / 128)), 256, 0, stream>>>(
        H1, W2T, b2, nullptr, W3, out, M, N2, K2);
}